// Round 2
// baseline (180.485 us; speedup 1.0000x reference)
//
#include <hip/hip_runtime.h>
#include <hip/hip_cooperative_groups.h>

namespace cg = cooperative_groups;

#define NPED 4096
#define SPLIT 32            // j-dimension splits
#define JC (NPED / SPLIT)   // 128 j's per chunk
#define BI 256              // i's per block (= blockDim)
#define NBLK (16 * SPLIT)   // 512 blocks
#define EPSF 1e-8f
#define DTF 0.4f
#define INV_MASS (1.0f/60.0f)
// mag = 10 * exp((0.6 - dist)/0.71) = exp2( C0 + C1*dist )
#define C1f (-2.0319648463225964f)   // -log2(e)/0.71
#define C0f (4.54110700268092f)      // log2(10) + 0.6*log2(e)/0.71
#define NLOG2E (-1.4426950408889634f)

__device__ __forceinline__ float rsqf(float x) { return __builtin_amdgcn_rsqf(x); }
__device__ __forceinline__ float ex2(float x)  { return __builtin_amdgcn_exp2f(x); }

__global__ __launch_bounds__(BI) void fused_kernel(const float4* __restrict__ state,
                                                   const float* __restrict__ cost_in,
                                                   const float4* __restrict__ stk,
                                                   const float2* __restrict__ goal,
                                                   const float* __restrict__ obs,
                                                   float* __restrict__ out,
                                                   float2* __restrict__ part) {
    cg::grid_group grid = cg::this_grid();
    const int t  = threadIdx.x;
    const int b  = blockIdx.x;
    const int ib = b & 15;    // i-block 0..15
    const int s  = b >> 4;    // j-split 0..31

    // ---- Phase 1: O(N^2) pairwise repulsion partials ----
    __shared__ float2 spos[JC];
    if (t < JC) {
        float4 r = state[s * JC + t];
        spos[t] = make_float2(r.x, r.y);
    }
    const int i = ib * BI + t;
    float4 me = state[i];
    __syncthreads();
    {
        const float xi = me.x, yi = me.y;
        float fx = 0.f, fy = 0.f;
        #pragma unroll 8
        for (int j = 0; j < JC; ++j) {
            float2 pj = spos[j];
            float dx = xi - pj.x;
            float dy = yi - pj.y;
            float d2 = fmaf(dx, dx, fmaf(dy, dy, EPSF));
            float inv = rsqf(d2);                        // 1/dist
            float dist = d2 * inv;
            float w = ex2(fmaf(dist, C1f, C0f)) * inv;   // mag/dist
            // j==i contributes exactly 0 (dx=dy=0 bitwise)
            fx = fmaf(w, dx, fx);
            fy = fmaf(w, dy, fy);
        }
        part[s * NPED + i] = make_float2(fx, fy);
    }

    grid.sync();

    // ---- Phase 2: blocks 0..15 reduce + integrate + write out & stacked ----
    if (b < 16) {
        const int ii = b * BI + t;
        float fx = 0.f, fy = 0.f;
        #pragma unroll
        for (int sp = 0; sp < SPLIT; ++sp) {
            float2 v = part[sp * NPED + ii];
            fx += v.x; fy += v.y;
        }
        fx *= INV_MASS; fy *= INV_MASS;          // rf
        float4 st = state[ii];
        float2 g  = goal[ii];
        float tx = g.x - st.x, ty = g.y - st.y;
        float invg = rsqf(fmaf(tx, tx, fmaf(ty, ty, EPSF)));
        float Fx = fx + 2.f * fmaf(tx, invg, -st.z);   // rf + af
        float Fy = fy + 2.f * fmaf(ty, invg, -st.w);
        float npx = fmaf(0.08f, Fx, fmaf(DTF, st.z, st.x));  // 0.5*DT^2 = 0.08
        float npy = fmaf(0.08f, Fy, fmaf(DTF, st.w, st.y));
        float nvx = fmaf(DTF, Fx, st.z);
        float nvy = fmaf(DTF, Fy, st.w);
        float invs = rsqf(fmaf(nvx, nvx, fmaf(nvy, nvy, EPSF)));
        float sc = fminf(1.f, invs);             // min(1, PED_SPEED/spd)
        nvx *= sc; nvy *= sc;
        ((float4*)out)[ii] = make_float4(npx, npy, nvx, nvy);
        // stacked = concat(stacked_in, state) at out offset N*4+1 (4B-aligned)
        float4 sv = stk[ii];
        float* o1 = out + (NPED * 4 + 1) + ii * 4;
        o1[0] = sv.x; o1[1] = sv.y; o1[2] = sv.z; o1[3] = sv.w;
        float* o2 = o1 + NPED * 4;
        o2[0] = st.x; o2[1] = st.y; o2[2] = st.z; o2[3] = st.w;
    }

    grid.sync();

    // ---- Phase 3: block 0 computes the cost scalar ----
    if (b == 0) {
        const float rx = out[0], ry = out[1];   // robot new pose
        float dev = 0.f, blame = 0.f;
        for (int k = 1 + t; k < NPED; k += BI) {
            float px = out[k * 4 + 0], py = out[k * 4 + 1];
            float ox = obs[k * 4 + 0], oy = obs[k * 4 + 1];
            float dxo = px - ox, dyo = py - oy;
            dev += sqrtf(fmaf(dxo, dxo, fmaf(dyo, dyo, EPSF)));
            float dxr = px - rx, dyr = py - ry;
            float d = sqrtf(fmaf(dxr, dxr, fmaf(dyr, dyr, EPSF)));
            blame += ex2(NLOG2E * d);           // exp(-d)
        }
        #pragma unroll
        for (int off = 32; off > 0; off >>= 1) {
            dev   += __shfl_down(dev, off);
            blame += __shfl_down(blame, off);
        }
        __shared__ float sd[4], sb[4];
        if ((t & 63) == 0) { sd[t >> 6] = dev; sb[t >> 6] = blame; }
        __syncthreads();
        if (t == 0) {
            float D = 0.f, B = 0.f;
            #pragma unroll
            for (int k = 0; k < 4; ++k) { D += sd[k]; B += sb[k]; }
            const float* stf = (const float*)state;
            const float* gf  = (const float*)goal;
            float gx = gf[0], gy = gf[1];
            float rix = stf[0], riy = stf[1];
            float a1x = rix - gx, a1y = riy - gy;
            float a2x = rx - gx,  a2y = ry - gy;
            float pg = sqrtf(fmaf(a1x, a1x, fmaf(a1y, a1y, EPSF)))
                     - sqrtf(fmaf(a2x, a2x, fmaf(a2y, a2y, EPSF)));
            out[NPED * 4] = cost_in[0] + 5.f * D + 2.f * B - pg;
        }
    }
}

extern "C" void kernel_launch(void* const* d_in, const int* in_sizes, int n_in,
                              void* d_out, int out_size, void* d_ws, size_t ws_size,
                              hipStream_t stream) {
    const float4* state = (const float4*)d_in[0];   // (N,4)
    const float*  cost  = (const float*)d_in[1];    // (1,)
    const float4* stk   = (const float4*)d_in[2];   // (N,4)
    const float2* goal  = (const float2*)d_in[3];   // (N,2)
    const float*  obs   = (const float*)d_in[4];    // (N,4)
    float* out   = (float*)d_out;                   // N*4 | 1 | 2N*4
    float2* part = (float2*)d_ws;                   // SPLIT*N float2 = 1 MiB

    void* args[] = {(void*)&state, (void*)&cost, (void*)&stk, (void*)&goal,
                    (void*)&obs, (void*)&out, (void*)&part};
    hipLaunchCooperativeKernel((void*)fused_kernel, dim3(NBLK), dim3(BI),
                               args, 0, stream);
}

// Round 3
// 73.078 us; speedup vs baseline: 2.4698x; 2.4698x over previous
//
#include <hip/hip_runtime.h>

#define NPED 4096
#define SPLIT 32            // j-dimension splits
#define JC (NPED / SPLIT)   // 128 j's per chunk
#define BI 256              // threads per block
#define EPSF 1e-8f
#define DTF 0.4f
#define INV_MASS (1.0f/60.0f)
// mag = 10 * exp((0.6 - dist)/0.71) = exp2( C0 + C1*dist )
#define C1f (-2.0319648463225964f)   // -log2(e)/0.71
#define C0f (4.54110700268092f)      // log2(10) + 0.6*log2(e)/0.71
#define NLOG2E (-1.4426950408889634f)

__device__ __forceinline__ float rsqf(float x) { return __builtin_amdgcn_rsqf(x); }
__device__ __forceinline__ float ex2(float x)  { return __builtin_amdgcn_exp2f(x); }

// ---- Kernel A: O(N^2) pairwise repulsion partials; seeds the cost cell ----
__global__ __launch_bounds__(BI) void forces_kernel(const float4* __restrict__ state,
                                                    const float* __restrict__ cost_in,
                                                    float2* __restrict__ part,
                                                    float* __restrict__ out) {
    __shared__ float2 spos[JC];
    const int t  = threadIdx.x;
    const int ib = blockIdx.x & 15;   // i-block 0..15
    const int s  = blockIdx.x >> 4;   // j-split 0..31
    if (t < JC) {
        float4 r = state[s * JC + t];
        spos[t] = make_float2(r.x, r.y);
    }
    if (blockIdx.x == 0 && t == 0) out[NPED * 4] = cost_in[0];  // seed cost
    const int i = ib * BI + t;
    float4 me = state[i];
    __syncthreads();
    const float xi = me.x, yi = me.y;
    float fx = 0.f, fy = 0.f;
    #pragma unroll 8
    for (int j = 0; j < JC; ++j) {
        float2 pj = spos[j];
        float dx = xi - pj.x;
        float dy = yi - pj.y;
        float d2 = fmaf(dx, dx, fmaf(dy, dy, EPSF));
        float inv = rsqf(d2);                        // 1/dist
        float dist = d2 * inv;
        float w = ex2(fmaf(dist, C1f, C0f)) * inv;   // mag/dist
        // j==i contributes exactly 0 (dx=dy=0 bitwise)
        fx = fmaf(w, dx, fx);
        fy = fmaf(w, dy, fy);
    }
    part[s * NPED + i] = make_float2(fx, fy);
}

// integrate one pedestrian given summed repulsion (fx,fy)
__device__ __forceinline__ float4 integrate_one(float4 st, float2 g,
                                                float fx, float fy) {
    fx *= INV_MASS; fy *= INV_MASS;          // rf
    float tx = g.x - st.x, ty = g.y - st.y;
    float invg = rsqf(fmaf(tx, tx, fmaf(ty, ty, EPSF)));
    float Fx = fx + 2.f * fmaf(tx, invg, -st.z);   // rf + af
    float Fy = fy + 2.f * fmaf(ty, invg, -st.w);
    float npx = fmaf(0.08f, Fx, fmaf(DTF, st.z, st.x));  // 0.5*DT^2 = 0.08
    float npy = fmaf(0.08f, Fy, fmaf(DTF, st.w, st.y));
    float nvx = fmaf(DTF, Fx, st.z);
    float nvy = fmaf(DTF, Fy, st.w);
    float invs = rsqf(fmaf(nvx, nvx, fmaf(nvy, nvy, EPSF)));
    float sc = fminf(1.f, invs);             // min(1, PED_SPEED/spd)
    return make_float4(npx, npy, nvx * sc, nvy * sc);
}

// ---- Kernel B: reduce + integrate + write out/stacked + cost (atomic) ----
__global__ __launch_bounds__(BI) void finish_kernel(const float4* __restrict__ state,
                                                    const float2* __restrict__ goal,
                                                    const float4* __restrict__ stk,
                                                    const float* __restrict__ obs,
                                                    const float2* __restrict__ part,
                                                    float* __restrict__ out) {
    const int t  = threadIdx.x;
    const int b  = blockIdx.x;     // 0..15
    const int ii = b * BI + t;

    // --- integrate my pedestrian ---
    float fx = 0.f, fy = 0.f;
    #pragma unroll
    for (int sp = 0; sp < SPLIT; ++sp) {
        float2 v = part[sp * NPED + ii];
        fx += v.x; fy += v.y;
    }
    float4 st = state[ii];
    float4 nw = integrate_one(st, goal[ii], fx, fy);
    ((float4*)out)[ii] = nw;

    // stacked = concat(stacked_in, state) at out offset N*4+1 (4B-aligned)
    float4 sv = stk[ii];
    float* o1 = out + (NPED * 4 + 1) + ii * 4;
    o1[0] = sv.x; o1[1] = sv.y; o1[2] = sv.z; o1[3] = sv.w;
    float* o2 = o1 + NPED * 4;
    o2[0] = st.x; o2[1] = st.y; o2[2] = st.z; o2[3] = st.w;

    // --- robot new pose, computed redundantly in every block (wave 0) ---
    __shared__ float2 rpose;
    if (t < 64) {
        float rfx = (t < SPLIT) ? part[t * NPED].x : 0.f;
        float rfy = (t < SPLIT) ? part[t * NPED].y : 0.f;
        #pragma unroll
        for (int off = 16; off > 0; off >>= 1) {
            rfx += __shfl_down(rfx, off);
            rfy += __shfl_down(rfy, off);
        }
        if (t == 0) {
            float4 r0 = integrate_one(state[0], goal[0], rfx, rfy);
            rpose = make_float2(r0.x, r0.y);
        }
    }
    __syncthreads();
    const float rx = rpose.x, ry = rpose.y;

    // --- dev/blame contribution for my pedestrian (skip robot ii==0) ---
    float c = 0.f;
    if (ii >= 1) {
        float ox = obs[ii * 4 + 0], oy = obs[ii * 4 + 1];
        float dxo = nw.x - ox, dyo = nw.y - oy;
        float dev = sqrtf(fmaf(dxo, dxo, fmaf(dyo, dyo, EPSF)));
        float dxr = nw.x - rx, dyr = nw.y - ry;
        float d = sqrtf(fmaf(dxr, dxr, fmaf(dyr, dyr, EPSF)));
        float blame = ex2(NLOG2E * d);          // exp(-d)
        c = fmaf(5.f, dev, 2.f * blame);        // A_COST*dev + B_COST*blame
    }
    #pragma unroll
    for (int off = 32; off > 0; off >>= 1) c += __shfl_down(c, off);
    __shared__ float sc4[4];
    if ((t & 63) == 0) sc4[t >> 6] = c;
    __syncthreads();
    if (t == 0) {
        float total = sc4[0] + sc4[1] + sc4[2] + sc4[3];
        if (b == 0) {
            const float* stf = (const float*)state;
            const float* gf  = (const float*)goal;
            float gx = gf[0], gy = gf[1];
            float a1x = stf[0] - gx, a1y = stf[1] - gy;
            float a2x = rx - gx,     a2y = ry - gy;
            float pg = sqrtf(fmaf(a1x, a1x, fmaf(a1y, a1y, EPSF)))
                     - sqrtf(fmaf(a2x, a2x, fmaf(a2y, a2y, EPSF)));
            total -= pg;
        }
        atomicAdd(out + NPED * 4, total);
    }
}

extern "C" void kernel_launch(void* const* d_in, const int* in_sizes, int n_in,
                              void* d_out, int out_size, void* d_ws, size_t ws_size,
                              hipStream_t stream) {
    const float4* state = (const float4*)d_in[0];   // (N,4)
    const float*  cost  = (const float*)d_in[1];    // (1,)
    const float4* stk   = (const float4*)d_in[2];   // (N,4)
    const float2* goal  = (const float2*)d_in[3];   // (N,2)
    const float*  obs   = (const float*)d_in[4];    // (N,4)
    float* out   = (float*)d_out;                   // N*4 | 1 | 2N*4
    float2* part = (float2*)d_ws;                   // SPLIT*N float2 = 1 MiB

    forces_kernel<<<dim3(16 * SPLIT), BI, 0, stream>>>(state, cost, part, out);
    finish_kernel<<<dim3(16), BI, 0, stream>>>(state, goal, stk, obs, part, out);
}